// Round 1
// baseline (2681.384 us; speedup 1.0000x reference)
//
#include <hip/hip_runtime.h>
#include <cstdint>

// GCN: out[g] = mean_{i in g}( norm_dst[i]*AGG2[i] + b2 ),  AGG2 = A·(h1s),
// h1s[j] = norm_src[j]*relu(norm_dst[j]*AGG1[j] + b1),      AGG1 = A·(norm_src·X@W1)
// Pooling commutes with @W2 -> second GEMM done on [G,128] only.

#define DD 128

__device__ __forceinline__ void gAtomAdd(float* p, float v) { unsafeAtomicAdd(p, v); }

// ---- degrees + per-graph counts ----
__global__ __launch_bounds__(256) void k_deg(const int* __restrict__ src, const int* __restrict__ dst,
                                             const int* __restrict__ gid,
                                             float* __restrict__ deg_out, float* __restrict__ deg_in,
                                             float* __restrict__ cnt, int E, int N, int G) {
  __shared__ float scnt[64];
  if (threadIdx.x < 64) scnt[threadIdx.x] = 0.f;
  __syncthreads();
  int stride = gridDim.x * blockDim.x;
  for (int i = blockIdx.x * blockDim.x + threadIdx.x; i < E; i += stride) {
    gAtomAdd(&deg_out[src[i]], 1.f);
    gAtomAdd(&deg_in[dst[i]], 1.f);
  }
  for (int i = blockIdx.x * blockDim.x + threadIdx.x; i < N; i += stride) {
    atomicAdd(&scnt[gid[i]], 1.f);   // LDS atomic
  }
  __syncthreads();
  if (threadIdx.x < (unsigned)G) {
    float v = scnt[threadIdx.x];
    if (v != 0.f) gAtomAdd(&cnt[threadIdx.x], v);
  }
}

// ---- norms + pooling weights ----
__global__ __launch_bounds__(256) void k_norm(const float* __restrict__ deg_out, const float* __restrict__ deg_in,
                                              const float* __restrict__ cnt, const int* __restrict__ gid,
                                              float* __restrict__ nsrc, float* __restrict__ ndst,
                                              float* __restrict__ poolw, int N) {
  int i = blockIdx.x * blockDim.x + threadIdx.x;
  if (i >= N) return;
  float go = deg_out[i]; go = go > 0.f ? go : 1.f;
  float gi = deg_in[i];  gi = gi > 0.f ? gi : 1.f;
  float ns = rsqrtf(go), nd = rsqrtf(gi);
  nsrc[i] = ns; ndst[i] = nd;
  float c = fmaxf(cnt[gid[i]], 1.f);
  poolw[i] = nd / c;
}

// ---- GEMM1: Z = (X @ W1) * nsrc[row]   (f32 vector ALU; 64x64 tile, 8x2/thread) ----
__global__ __launch_bounds__(256) void k_gemm1(const float* __restrict__ X, const float* __restrict__ W,
                                               const float* __restrict__ nsrc, float* __restrict__ Z, int N) {
  __shared__ float Wl[128 * 64];   // 32 KB: W[:, ch*64 .. ch*64+63]
  __shared__ float Xl[64 * 128];   // 32 KB
  int bid = blockIdx.x;
  int rb = bid >> 1, ch = bid & 1;
  int row0 = rb * 64;
  int t = threadIdx.x;
  for (int i = t; i < 128 * 16; i += 256) {           // 2048 float4 = W half
    int r = i >> 4, c4 = i & 15;
    float4 v = *(const float4*)(W + r * 128 + ch * 64 + c4 * 4);
    *(float4*)(Wl + r * 64 + c4 * 4) = v;
  }
  for (int i = t; i < 64 * 32; i += 256) {            // 2048 float4 = X tile
    int r = i >> 5, c4 = i & 31;
    int row = row0 + r; if (row >= N) row = N - 1;
    float4 v = *(const float4*)(X + (size_t)row * 128 + c4 * 4);
    *(float4*)(Xl + r * 128 + c4 * 4) = v;
  }
  __syncthreads();
  int tx = t & 31, ty = t >> 5;
  float acc[8][2] = {};
  for (int k = 0; k < 128; k += 4) {
    float4 xv[8];
#pragma unroll
    for (int rr = 0; rr < 8; ++rr) xv[rr] = *(const float4*)(Xl + (ty * 8 + rr) * 128 + k);
#pragma unroll
    for (int kk = 0; kk < 4; ++kk) {
      float w0 = Wl[(k + kk) * 64 + tx];
      float w1 = Wl[(k + kk) * 64 + tx + 32];
#pragma unroll
      for (int rr = 0; rr < 8; ++rr) {
        float x = ((const float*)&xv[rr])[kk];
        acc[rr][0] = fmaf(x, w0, acc[rr][0]);
        acc[rr][1] = fmaf(x, w1, acc[rr][1]);
      }
    }
  }
#pragma unroll
  for (int rr = 0; rr < 8; ++rr) {
    int row = row0 + ty * 8 + rr;
    if (row < N) {
      float s = nsrc[row];
      Z[(size_t)row * 128 + ch * 64 + tx]      = acc[rr][0] * s;
      Z[(size_t)row * 128 + ch * 64 + tx + 32] = acc[rr][1] * s;
    }
  }
}

// ---- layer-1 scatter: AGG[dst] += Z[src]  (one wave per edge, float2/lane) ----
__global__ __launch_bounds__(256) void k_scatter1(const float* __restrict__ Z, const int* __restrict__ src,
                                                  const int* __restrict__ dst, float* __restrict__ AGG, int E) {
  int lane = threadIdx.x & 63;
  int wid = (blockIdx.x * blockDim.x + threadIdx.x) >> 6;
  int nw = (gridDim.x * blockDim.x) >> 6;
  for (int e = wid; e < E; e += nw) {
    int s = src[e], d = dst[e];
    float2 v = *(const float2*)(Z + (size_t)s * 128 + lane * 2);
    float* a = AGG + (size_t)d * 128 + lane * 2;
    gAtomAdd(a, v.x);
    gAtomAdd(a + 1, v.y);
  }
}

// ---- h1s = nsrc * relu(ndst*AGG + b1) ----
__global__ __launch_bounds__(256) void k_post1(const float* __restrict__ AGG, const float* __restrict__ b1,
                                               const float* __restrict__ nsrc, const float* __restrict__ ndst,
                                               float* __restrict__ H, int N) {
  int t = blockIdx.x * blockDim.x + threadIdx.x;
  if (t >= N * 32) return;
  int i = t >> 5, c4 = t & 31;
  float4 a = *(const float4*)(AGG + (size_t)i * 128 + c4 * 4);
  float4 b = *(const float4*)(b1 + c4 * 4);
  float nd = ndst[i], ns = nsrc[i];
  float4 r;
  r.x = fmaxf(fmaf(nd, a.x, b.x), 0.f) * ns;
  r.y = fmaxf(fmaf(nd, a.y, b.y), 0.f) * ns;
  r.z = fmaxf(fmaf(nd, a.z, b.z), 0.f) * ns;
  r.w = fmaxf(fmaf(nd, a.w, b.w), 0.f) * ns;
  *(float4*)(H + (size_t)i * 128 + c4 * 4) = r;
}

// ---- layer-2 scatter fused with pooling: pooled[g] += poolw[dst] * H[src], LDS accum ----
__global__ __launch_bounds__(256) void k_scatter2(const float* __restrict__ H, const int* __restrict__ src,
                                                  const int* __restrict__ dst, const int* __restrict__ gid,
                                                  const float* __restrict__ poolw, float* __restrict__ pooled,
                                                  int E, int G) {
  __shared__ float acc[64 * 128];  // 32 KB
  int GD = G * 128;
  for (int i = threadIdx.x; i < GD; i += blockDim.x) acc[i] = 0.f;
  __syncthreads();
  int lane = threadIdx.x & 63;
  int wid = (blockIdx.x * blockDim.x + threadIdx.x) >> 6;
  int nw = (gridDim.x * blockDim.x) >> 6;
  for (int e = wid; e < E; e += nw) {
    int s = src[e], d = dst[e];
    float w = poolw[d];
    int g = gid[d];
    float2 v = *(const float2*)(H + (size_t)s * 128 + lane * 2);
    float* ap = acc + g * 128 + lane * 2;
    atomicAdd(ap, w * v.x);        // ds_add_f32
    atomicAdd(ap + 1, w * v.y);
  }
  __syncthreads();
  for (int i = threadIdx.x; i < GD; i += blockDim.x) {
    float v = acc[i];
    if (v != 0.f) gAtomAdd(&pooled[i], v);
  }
}

// ---- out = pooled @ W2 + b2  (tiny 64x128x128 GEMM) ----
__global__ __launch_bounds__(128) void k_out(const float* __restrict__ pooled, const float* __restrict__ W2,
                                             const float* __restrict__ b2, float* __restrict__ out) {
  __shared__ float p[128];
  int g = blockIdx.x, d = threadIdx.x;
  p[d] = pooled[g * 128 + d];
  __syncthreads();
  float a = b2[d];
#pragma unroll 4
  for (int k = 0; k < 128; ++k) a = fmaf(p[k], W2[k * 128 + d], a);
  out[g * 128 + d] = a;
}

extern "C" void kernel_launch(void* const* d_in, const int* in_sizes, int n_in,
                              void* d_out, int out_size, void* d_ws, size_t ws_size,
                              hipStream_t stream) {
  const float* X  = (const float*)d_in[0];
  const float* W1 = (const float*)d_in[1];
  const float* b1 = (const float*)d_in[2];
  const float* W2 = (const float*)d_in[3];
  const float* b2 = (const float*)d_in[4];
  const int* src  = (const int*)d_in[5];
  const int* dst  = (const int*)d_in[6];
  const int* gid  = (const int*)d_in[7];
  int E = in_sizes[5];
  int N = in_sizes[7];
  int G = out_size / DD;   // 64

  float* ws = (float*)d_ws;
  size_t o = 0;
  float* deg_out = ws + o; o += N;
  float* deg_in  = ws + o; o += N;
  float* cnt     = ws + o; o += G;
  float* pooled  = ws + o; o += (size_t)G * DD;
  float* AGG     = ws + o; o += (size_t)N * DD;
  size_t zeroElems = o;                      // everything above must start at 0
  float* nsrc  = ws + o; o += N;
  float* ndst  = ws + o; o += N;
  float* poolw = ws + o; o += N;
  float* BUF   = ws + o; o += (size_t)N * DD;  // Z1s, later h1s

  hipMemsetAsync(d_ws, 0, zeroElems * sizeof(float), stream);

  k_deg<<<1024, 256, 0, stream>>>(src, dst, gid, deg_out, deg_in, cnt, E, N, G);
  k_norm<<<(N + 255) / 256, 256, 0, stream>>>(deg_out, deg_in, cnt, gid, nsrc, ndst, poolw, N);
  int rb = (N + 63) / 64;
  k_gemm1<<<rb * 2, 256, 0, stream>>>(X, W1, nsrc, BUF, N);
  k_scatter1<<<2048, 256, 0, stream>>>(BUF, src, dst, AGG, E);
  k_post1<<<(N * 32 + 255) / 256, 256, 0, stream>>>(AGG, b1, nsrc, ndst, BUF, N);
  k_scatter2<<<512, 256, 0, stream>>>(BUF, src, dst, gid, poolw, pooled, E, G);
  k_out<<<G, 128, 0, stream>>>(pooled, W2, b2, (float*)d_out);
}

// Round 2
// 759.237 us; speedup vs baseline: 3.5317x; 3.5317x over previous
//
#include <hip/hip_runtime.h>
#include <cstdint>

// GCN via CSR (edges counting-sorted by dst) — no per-edge global f32 atomics.
// out[g] = mean_{i in g}( ndst[i]*AGG2[i] + b2 ),  AGG2 = A·h1s
// h1s[j] = nsrc[j]*relu(ndst[j]*AGG1[j] + b1),     AGG1 = A·(nsrc·X@W1)
// Pooling commutes with @W2 -> final GEMM is [G,128]x[128,128] only.

#define DD 128

__device__ __forceinline__ void gAtomAdd(float* p, float v) { unsafeAtomicAdd(p, v); }

// ---- histograms: deg_out, deg_in (int), per-graph node counts ----
__global__ __launch_bounds__(256) void k_deg(const int* __restrict__ src, const int* __restrict__ dst,
                                             const int* __restrict__ gid,
                                             int* __restrict__ degO, int* __restrict__ degI,
                                             int* __restrict__ gcnt, int E, int N, int G) {
  __shared__ int scnt[64];
  if (threadIdx.x < 64) scnt[threadIdx.x] = 0;
  __syncthreads();
  int stride = gridDim.x * blockDim.x;
  for (int i = blockIdx.x * blockDim.x + threadIdx.x; i < E; i += stride) {
    atomicAdd(&degO[src[i]], 1);
    atomicAdd(&degI[dst[i]], 1);
  }
  for (int i = blockIdx.x * blockDim.x + threadIdx.x; i < N; i += stride)
    atomicAdd(&scnt[gid[i]], 1);
  __syncthreads();
  if (threadIdx.x < (unsigned)G) {
    int v = scnt[threadIdx.x];
    if (v) atomicAdd(&gcnt[threadIdx.x], v);
  }
}

// ---- norms + pooling weights ----
__global__ __launch_bounds__(256) void k_norm(const int* __restrict__ degO, const int* __restrict__ degI,
                                              const int* __restrict__ gcnt, const int* __restrict__ gid,
                                              float* __restrict__ nsrc, float* __restrict__ ndst,
                                              float* __restrict__ poolw, int N) {
  int i = blockIdx.x * blockDim.x + threadIdx.x;
  if (i >= N) return;
  float go = (float)degO[i]; go = go > 0.f ? go : 1.f;
  float gi = (float)degI[i]; gi = gi > 0.f ? gi : 1.f;
  float ns = rsqrtf(go), nd = rsqrtf(gi);
  nsrc[i] = ns; ndst[i] = nd;
  float c = (float)gcnt[gid[i]]; c = c > 1.f ? c : 1.f;
  poolw[i] = nd / c;
}

// ---- scan phase A: per-block inclusive scan of degI, emit exclusive + block sums ----
__global__ __launch_bounds__(256) void k_scanA(const int* __restrict__ degI, int* __restrict__ offs,
                                               int* __restrict__ bsum, int N) {
  __shared__ int s[256];
  int i = blockIdx.x * 256 + threadIdx.x;
  int v = (i < N) ? degI[i] : 0;
  s[threadIdx.x] = v;
  __syncthreads();
  for (int off = 1; off < 256; off <<= 1) {
    int x = (threadIdx.x >= off) ? s[threadIdx.x - off] : 0;
    __syncthreads();
    s[threadIdx.x] += x;
    __syncthreads();
  }
  if (i < N) offs[i] = s[threadIdx.x] - v;        // exclusive, block-local
  if (threadIdx.x == 255) bsum[blockIdx.x] = s[255];
}

// ---- scan phase B: single-block exclusive scan of block sums (B <= 1024) ----
__global__ __launch_bounds__(1024) void k_scanB(int* __restrict__ bsum, int B) {
  __shared__ int s[1024];
  int v = (threadIdx.x < (unsigned)B) ? bsum[threadIdx.x] : 0;
  s[threadIdx.x] = v;
  __syncthreads();
  for (int off = 1; off < 1024; off <<= 1) {
    int x = (threadIdx.x >= off) ? s[threadIdx.x - off] : 0;
    __syncthreads();
    s[threadIdx.x] += x;
    __syncthreads();
  }
  if (threadIdx.x < (unsigned)B) bsum[threadIdx.x] = s[threadIdx.x] - v;  // exclusive
}

// ---- scan phase C: add block offsets; produce offsets + cursor copy ----
__global__ __launch_bounds__(256) void k_scanC(int* __restrict__ offs, const int* __restrict__ bsum,
                                               int* __restrict__ cursor, int N, int E) {
  int i = blockIdx.x * 256 + threadIdx.x;
  if (i < N) {
    int o = offs[i] + bsum[blockIdx.x];
    offs[i] = o;
    cursor[i] = o;
  }
  if (i == 0) offs[N] = E;
}

// ---- placement: bucket src indices by dst ----
__global__ __launch_bounds__(256) void k_place(const int* __restrict__ src, const int* __restrict__ dst,
                                               int* __restrict__ cursor, int* __restrict__ srcS, int E) {
  int stride = gridDim.x * blockDim.x;
  for (int e = blockIdx.x * blockDim.x + threadIdx.x; e < E; e += stride) {
    int d = dst[e];
    int p = atomicAdd(&cursor[d], 1);
    srcS[p] = src[e];
  }
}

// ---- GEMM1: Z = (X @ W1) * nsrc[row]   (f32 vector ALU; 64x64 tile, 8x2/thread) ----
__global__ __launch_bounds__(256) void k_gemm1(const float* __restrict__ X, const float* __restrict__ W,
                                               const float* __restrict__ nsrc, float* __restrict__ Z, int N) {
  __shared__ float Wl[128 * 64];
  __shared__ float Xl[64 * 128];
  int bid = blockIdx.x;
  int rb = bid >> 1, ch = bid & 1;
  int row0 = rb * 64;
  int t = threadIdx.x;
  for (int i = t; i < 128 * 16; i += 256) {
    int r = i >> 4, c4 = i & 15;
    float4 v = *(const float4*)(W + r * 128 + ch * 64 + c4 * 4);
    *(float4*)(Wl + r * 64 + c4 * 4) = v;
  }
  for (int i = t; i < 64 * 32; i += 256) {
    int r = i >> 5, c4 = i & 31;
    int row = row0 + r; if (row >= N) row = N - 1;
    float4 v = *(const float4*)(X + (size_t)row * 128 + c4 * 4);
    *(float4*)(Xl + r * 128 + c4 * 4) = v;
  }
  __syncthreads();
  int tx = t & 31, ty = t >> 5;
  float acc[8][2] = {};
  for (int k = 0; k < 128; k += 4) {
    float4 xv[8];
#pragma unroll
    for (int rr = 0; rr < 8; ++rr) xv[rr] = *(const float4*)(Xl + (ty * 8 + rr) * 128 + k);
#pragma unroll
    for (int kk = 0; kk < 4; ++kk) {
      float w0 = Wl[(k + kk) * 64 + tx];
      float w1 = Wl[(k + kk) * 64 + tx + 32];
#pragma unroll
      for (int rr = 0; rr < 8; ++rr) {
        float x = ((const float*)&xv[rr])[kk];
        acc[rr][0] = fmaf(x, w0, acc[rr][0]);
        acc[rr][1] = fmaf(x, w1, acc[rr][1]);
      }
    }
  }
#pragma unroll
  for (int rr = 0; rr < 8; ++rr) {
    int row = row0 + ty * 8 + rr;
    if (row < N) {
      float s = nsrc[row];
      Z[(size_t)row * 128 + ch * 64 + tx]      = acc[rr][0] * s;
      Z[(size_t)row * 128 + ch * 64 + tx + 32] = acc[rr][1] * s;
    }
  }
}

// ---- layer1: per-dst gather-reduce + fused post-op.  H[d] = nsrc[d]*relu(ndst[d]*sum + b1) ----
__global__ __launch_bounds__(256) void k_layer1(const float* __restrict__ Z, const int* __restrict__ offs,
                                                const int* __restrict__ srcS, const float* __restrict__ b1,
                                                const float* __restrict__ nsrc, const float* __restrict__ ndst,
                                                float* __restrict__ H, int N) {
  int lane = threadIdx.x & 63;
  int d = blockIdx.x * 4 + (threadIdx.x >> 6);
  if (d >= N) return;
  int start = offs[d], end = offs[d + 1];
  float ax = 0.f, ay = 0.f;
  int e = start;
  for (; e + 4 <= end; e += 4) {
    int s0 = srcS[e], s1 = srcS[e + 1], s2 = srcS[e + 2], s3 = srcS[e + 3];
    float2 v0 = *(const float2*)(Z + (size_t)s0 * 128 + lane * 2);
    float2 v1 = *(const float2*)(Z + (size_t)s1 * 128 + lane * 2);
    float2 v2 = *(const float2*)(Z + (size_t)s2 * 128 + lane * 2);
    float2 v3 = *(const float2*)(Z + (size_t)s3 * 128 + lane * 2);
    ax += v0.x + v1.x + v2.x + v3.x;
    ay += v0.y + v1.y + v2.y + v3.y;
  }
  for (; e < end; ++e) {
    int s = srcS[e];
    float2 v = *(const float2*)(Z + (size_t)s * 128 + lane * 2);
    ax += v.x; ay += v.y;
  }
  float nd = ndst[d], ns = nsrc[d];
  float bx = b1[lane * 2], by = b1[lane * 2 + 1];
  float2 h;
  h.x = fmaxf(fmaf(nd, ax, bx), 0.f) * ns;
  h.y = fmaxf(fmaf(nd, ay, by), 0.f) * ns;
  *(float2*)(H + (size_t)d * 128 + lane * 2) = h;
}

// ---- layer2: per-dst gather-reduce, weighted LDS pool accumulate, one flush per block ----
__global__ __launch_bounds__(256) void k_layer2(const float* __restrict__ H, const int* __restrict__ offs,
                                                const int* __restrict__ srcS, const int* __restrict__ gid,
                                                const float* __restrict__ poolw, float* __restrict__ pooled,
                                                int N, int G) {
  __shared__ float acc[64 * DD];  // 32 KB
  int GD = G * DD;
  for (int i = threadIdx.x; i < GD; i += blockDim.x) acc[i] = 0.f;
  __syncthreads();
  int lane = threadIdx.x & 63;
  int wid = (blockIdx.x * blockDim.x + threadIdx.x) >> 6;
  int nw = (gridDim.x * blockDim.x) >> 6;
  for (int d = wid; d < N; d += nw) {
    int start = offs[d], end = offs[d + 1];
    float ax = 0.f, ay = 0.f;
    int e = start;
    for (; e + 4 <= end; e += 4) {
      int s0 = srcS[e], s1 = srcS[e + 1], s2 = srcS[e + 2], s3 = srcS[e + 3];
      float2 v0 = *(const float2*)(H + (size_t)s0 * 128 + lane * 2);
      float2 v1 = *(const float2*)(H + (size_t)s1 * 128 + lane * 2);
      float2 v2 = *(const float2*)(H + (size_t)s2 * 128 + lane * 2);
      float2 v3 = *(const float2*)(H + (size_t)s3 * 128 + lane * 2);
      ax += v0.x + v1.x + v2.x + v3.x;
      ay += v0.y + v1.y + v2.y + v3.y;
    }
    for (; e < end; ++e) {
      int s = srcS[e];
      float2 v = *(const float2*)(H + (size_t)s * 128 + lane * 2);
      ax += v.x; ay += v.y;
    }
    float w = poolw[d];
    int g = gid[d];
    float* ap = acc + g * DD + lane * 2;
    atomicAdd(ap, w * ax);       // ds_add_f32
    atomicAdd(ap + 1, w * ay);
  }
  __syncthreads();
  for (int i = threadIdx.x; i < GD; i += blockDim.x) {
    float v = acc[i];
    if (v != 0.f) gAtomAdd(&pooled[i], v);
  }
}

// ---- out = pooled @ W2 + b2  (tiny 64x128x128 GEMM) ----
__global__ __launch_bounds__(128) void k_out(const float* __restrict__ pooled, const float* __restrict__ W2,
                                             const float* __restrict__ b2, float* __restrict__ out) {
  __shared__ float p[DD];
  int g = blockIdx.x, d = threadIdx.x;
  p[d] = pooled[g * DD + d];
  __syncthreads();
  float a = b2[d];
#pragma unroll 4
  for (int k = 0; k < DD; ++k) a = fmaf(p[k], W2[k * DD + d], a);
  out[g * DD + d] = a;
}

extern "C" void kernel_launch(void* const* d_in, const int* in_sizes, int n_in,
                              void* d_out, int out_size, void* d_ws, size_t ws_size,
                              hipStream_t stream) {
  const float* X  = (const float*)d_in[0];
  const float* W1 = (const float*)d_in[1];
  const float* b1 = (const float*)d_in[2];
  const float* W2 = (const float*)d_in[3];
  const float* b2 = (const float*)d_in[4];
  const int* src  = (const int*)d_in[5];
  const int* dst  = (const int*)d_in[6];
  const int* gid  = (const int*)d_in[7];
  int E = in_sizes[5];
  int N = in_sizes[7];
  int G = out_size / DD;   // 64

  char* w = (char*)d_ws;
  size_t o = 0;
  auto carve = [&](size_t bytes) { char* p = w + o; o += (bytes + 255) & ~(size_t)255; return p; };
  // zero-init region (contiguous at start)
  int*   degO   = (int*)  carve((size_t)N * 4);
  int*   degI   = (int*)  carve((size_t)N * 4);
  int*   gcnt   = (int*)  carve((size_t)G * 4);
  float* pooled = (float*)carve((size_t)G * DD * 4);
  size_t zeroBytes = o;
  // rest
  float* nsrc   = (float*)carve((size_t)N * 4);
  float* ndst   = (float*)carve((size_t)N * 4);
  float* poolw  = (float*)carve((size_t)N * 4);
  int*   offs   = (int*)  carve((size_t)(N + 1) * 4);
  int*   cursor = (int*)  carve((size_t)N * 4);
  int*   bsum   = (int*)  carve(1024 * 4);
  int*   srcS   = (int*)  carve((size_t)E * 4);
  float* Z      = (float*)carve((size_t)N * DD * 4);
  float* H      = (float*)carve((size_t)N * DD * 4);

  hipMemsetAsync(d_ws, 0, zeroBytes, stream);

  k_deg<<<1024, 256, 0, stream>>>(src, dst, gid, degO, degI, gcnt, E, N, G);
  k_norm<<<(N + 255) / 256, 256, 0, stream>>>(degO, degI, gcnt, gid, nsrc, ndst, poolw, N);
  int B = (N + 255) / 256;                  // scan blocks (must be <= 1024)
  k_scanA<<<B, 256, 0, stream>>>(degI, offs, bsum, N);
  k_scanB<<<1, 1024, 0, stream>>>(bsum, B);
  k_scanC<<<B, 256, 0, stream>>>(offs, bsum, cursor, N, E);
  k_place<<<1024, 256, 0, stream>>>(src, dst, cursor, srcS, E);
  int rb = (N + 63) / 64;
  k_gemm1<<<rb * 2, 256, 0, stream>>>(X, W1, nsrc, Z, N);
  k_layer1<<<(N + 3) / 4, 256, 0, stream>>>(Z, offs, srcS, b1, nsrc, ndst, H, N);
  k_layer2<<<512, 256, 0, stream>>>(H, offs, srcS, gid, poolw, pooled, N, G);
  k_out<<<G, DD, 0, stream>>>(pooled, W2, b2, (float*)d_out);
}

// Round 3
// 691.977 us; speedup vs baseline: 3.8750x; 1.0972x over previous
//
#include <hip/hip_runtime.h>
#include <cstdint>

// GCN via CSR (edges counting-sorted by dst) — no per-edge global f32 atomics.
// out[g] = mean_{i in g}( ndst[i]*AGG2[i] + b2 ),  AGG2 = A·h1s
// h1s[j] = nsrc[j]*relu(ndst[j]*AGG1[j] + b1),     AGG1 = A·(nsrc·X@W1)
// Pooling commutes with @W2 -> final GEMM is [G,128]x[128,128] only.

#define DD 128

__device__ __forceinline__ void gAtomAdd(float* p, float v) { unsafeAtomicAdd(p, v); }

// ---- histograms: deg_out, deg_in (int), per-graph node counts ----
__global__ __launch_bounds__(256) void k_deg(const int* __restrict__ src, const int* __restrict__ dst,
                                             const int* __restrict__ gid,
                                             int* __restrict__ degO, int* __restrict__ degI,
                                             int* __restrict__ gcnt, int E, int N, int G) {
  __shared__ int scnt[64];
  if (threadIdx.x < 64) scnt[threadIdx.x] = 0;
  __syncthreads();
  int stride = gridDim.x * blockDim.x;
  for (int i = blockIdx.x * blockDim.x + threadIdx.x; i < E; i += stride) {
    atomicAdd(&degO[src[i]], 1);
    atomicAdd(&degI[dst[i]], 1);
  }
  for (int i = blockIdx.x * blockDim.x + threadIdx.x; i < N; i += stride)
    atomicAdd(&scnt[gid[i]], 1);
  __syncthreads();
  if (threadIdx.x < (unsigned)G) {
    int v = scnt[threadIdx.x];
    if (v) atomicAdd(&gcnt[threadIdx.x], v);
  }
}

// ---- norms + pooling weights ----
__global__ __launch_bounds__(256) void k_norm(const int* __restrict__ degO, const int* __restrict__ degI,
                                              const int* __restrict__ gcnt, const int* __restrict__ gid,
                                              float* __restrict__ nsrc, float* __restrict__ ndst,
                                              float* __restrict__ poolw, int N) {
  int i = blockIdx.x * blockDim.x + threadIdx.x;
  if (i >= N) return;
  float go = (float)degO[i]; go = go > 0.f ? go : 1.f;
  float gi = (float)degI[i]; gi = gi > 0.f ? gi : 1.f;
  float ns = rsqrtf(go), nd = rsqrtf(gi);
  nsrc[i] = ns; ndst[i] = nd;
  float c = (float)gcnt[gid[i]]; c = c > 1.f ? c : 1.f;
  poolw[i] = nd / c;
}

// ---- scan phase A: per-block inclusive scan of degI, emit exclusive + block sums ----
__global__ __launch_bounds__(256) void k_scanA(const int* __restrict__ degI, int* __restrict__ offs,
                                               int* __restrict__ bsum, int N) {
  __shared__ int s[256];
  int i = blockIdx.x * 256 + threadIdx.x;
  int v = (i < N) ? degI[i] : 0;
  s[threadIdx.x] = v;
  __syncthreads();
  for (int off = 1; off < 256; off <<= 1) {
    int x = (threadIdx.x >= off) ? s[threadIdx.x - off] : 0;
    __syncthreads();
    s[threadIdx.x] += x;
    __syncthreads();
  }
  if (i < N) offs[i] = s[threadIdx.x] - v;        // exclusive, block-local
  if (threadIdx.x == 255) bsum[blockIdx.x] = s[255];
}

// ---- scan phase B: single-block exclusive scan of block sums (B <= 1024) ----
__global__ __launch_bounds__(1024) void k_scanB(int* __restrict__ bsum, int B) {
  __shared__ int s[1024];
  int v = (threadIdx.x < (unsigned)B) ? bsum[threadIdx.x] : 0;
  s[threadIdx.x] = v;
  __syncthreads();
  for (int off = 1; off < 1024; off <<= 1) {
    int x = (threadIdx.x >= off) ? s[threadIdx.x - off] : 0;
    __syncthreads();
    s[threadIdx.x] += x;
    __syncthreads();
  }
  if (threadIdx.x < (unsigned)B) bsum[threadIdx.x] = s[threadIdx.x] - v;  // exclusive
}

// ---- scan phase C: add block offsets; produce offsets + cursor copy ----
__global__ __launch_bounds__(256) void k_scanC(int* __restrict__ offs, const int* __restrict__ bsum,
                                               int* __restrict__ cursor, int N, int E) {
  int i = blockIdx.x * 256 + threadIdx.x;
  if (i < N) {
    int o = offs[i] + bsum[blockIdx.x];
    offs[i] = o;
    cursor[i] = o;
  }
  if (i == 0) offs[N] = E;
}

// ---- placement: bucket src indices by dst ----
__global__ __launch_bounds__(256) void k_place(const int* __restrict__ src, const int* __restrict__ dst,
                                               int* __restrict__ cursor, int* __restrict__ srcS, int E) {
  int stride = gridDim.x * blockDim.x;
  for (int e = blockIdx.x * blockDim.x + threadIdx.x; e < E; e += stride) {
    int d = dst[e];
    int p = atomicAdd(&cursor[d], 1);
    srcS[p] = src[e];
  }
}

// ---- GEMM1: Z = (X @ W1) * nsrc[row]   (f32 vector ALU; 64x64 tile, 8x2/thread) ----
__global__ __launch_bounds__(256) void k_gemm1(const float* __restrict__ X, const float* __restrict__ W,
                                               const float* __restrict__ nsrc, float* __restrict__ Z, int N) {
  __shared__ float Wl[128 * 64];
  __shared__ float Xl[64 * 128];
  int bid = blockIdx.x;
  int rb = bid >> 1, ch = bid & 1;
  int row0 = rb * 64;
  int t = threadIdx.x;
  for (int i = t; i < 128 * 16; i += 256) {
    int r = i >> 4, c4 = i & 15;
    float4 v = *(const float4*)(W + r * 128 + ch * 64 + c4 * 4);
    *(float4*)(Wl + r * 64 + c4 * 4) = v;
  }
  for (int i = t; i < 64 * 32; i += 256) {
    int r = i >> 5, c4 = i & 31;
    int row = row0 + r; if (row >= N) row = N - 1;
    float4 v = *(const float4*)(X + (size_t)row * 128 + c4 * 4);
    *(float4*)(Xl + r * 128 + c4 * 4) = v;
  }
  __syncthreads();
  int tx = t & 31, ty = t >> 5;
  float acc[8][2] = {};
  for (int k = 0; k < 128; k += 4) {
    float4 xv[8];
#pragma unroll
    for (int rr = 0; rr < 8; ++rr) xv[rr] = *(const float4*)(Xl + (ty * 8 + rr) * 128 + k);
#pragma unroll
    for (int kk = 0; kk < 4; ++kk) {
      float w0 = Wl[(k + kk) * 64 + tx];
      float w1 = Wl[(k + kk) * 64 + tx + 32];
#pragma unroll
      for (int rr = 0; rr < 8; ++rr) {
        float x = ((const float*)&xv[rr])[kk];
        acc[rr][0] = fmaf(x, w0, acc[rr][0]);
        acc[rr][1] = fmaf(x, w1, acc[rr][1]);
      }
    }
  }
#pragma unroll
  for (int rr = 0; rr < 8; ++rr) {
    int row = row0 + ty * 8 + rr;
    if (row < N) {
      float s = nsrc[row];
      Z[(size_t)row * 128 + ch * 64 + tx]      = acc[rr][0] * s;
      Z[(size_t)row * 128 + ch * 64 + tx + 32] = acc[rr][1] * s;
    }
  }
}

// ---- layer1: per-dst gather-reduce + fused post-op.  H[d] = nsrc[d]*relu(ndst[d]*sum + b1) ----
// unroll 8: 8 rows (4 KB) in flight per wave
__global__ __launch_bounds__(256) void k_layer1(const float* __restrict__ Z, const int* __restrict__ offs,
                                                const int* __restrict__ srcS, const float* __restrict__ b1,
                                                const float* __restrict__ nsrc, const float* __restrict__ ndst,
                                                float* __restrict__ H, int N) {
  int lane = threadIdx.x & 63;
  int d = blockIdx.x * 4 + (threadIdx.x >> 6);
  if (d >= N) return;
  int start = offs[d], end = offs[d + 1];
  float ax = 0.f, ay = 0.f;
  int e = start;
  for (; e + 8 <= end; e += 8) {
    int s0 = srcS[e],     s1 = srcS[e + 1], s2 = srcS[e + 2], s3 = srcS[e + 3];
    int s4 = srcS[e + 4], s5 = srcS[e + 5], s6 = srcS[e + 6], s7 = srcS[e + 7];
    float2 v0 = *(const float2*)(Z + (size_t)s0 * 128 + lane * 2);
    float2 v1 = *(const float2*)(Z + (size_t)s1 * 128 + lane * 2);
    float2 v2 = *(const float2*)(Z + (size_t)s2 * 128 + lane * 2);
    float2 v3 = *(const float2*)(Z + (size_t)s3 * 128 + lane * 2);
    float2 v4 = *(const float2*)(Z + (size_t)s4 * 128 + lane * 2);
    float2 v5 = *(const float2*)(Z + (size_t)s5 * 128 + lane * 2);
    float2 v6 = *(const float2*)(Z + (size_t)s6 * 128 + lane * 2);
    float2 v7 = *(const float2*)(Z + (size_t)s7 * 128 + lane * 2);
    ax += ((v0.x + v1.x) + (v2.x + v3.x)) + ((v4.x + v5.x) + (v6.x + v7.x));
    ay += ((v0.y + v1.y) + (v2.y + v3.y)) + ((v4.y + v5.y) + (v6.y + v7.y));
  }
  for (; e < end; ++e) {
    int s = srcS[e];
    float2 v = *(const float2*)(Z + (size_t)s * 128 + lane * 2);
    ax += v.x; ay += v.y;
  }
  float nd = ndst[d], ns = nsrc[d];
  float bx = b1[lane * 2], by = b1[lane * 2 + 1];
  float2 h;
  h.x = fmaxf(fmaf(nd, ax, bx), 0.f) * ns;
  h.y = fmaxf(fmaf(nd, ay, by), 0.f) * ns;
  *(float2*)(H + (size_t)d * 128 + lane * 2) = h;
}

// ---- layer2: per-dst gather-reduce, weighted LDS pool accumulate, one flush per block ----
// block=1024 (16 waves): grid 512 -> 2 blocks/CU, 64 KB LDS/CU, 32 waves/CU = 100% occ
__global__ __launch_bounds__(1024, 8) void k_layer2(const float* __restrict__ H, const int* __restrict__ offs,
                                                    const int* __restrict__ srcS, const int* __restrict__ gid,
                                                    const float* __restrict__ poolw, float* __restrict__ pooled,
                                                    int N, int G) {
  __shared__ float acc[64 * DD];  // 32 KB
  int GD = G * DD;
  for (int i = threadIdx.x; i < GD; i += blockDim.x) acc[i] = 0.f;
  __syncthreads();
  int lane = threadIdx.x & 63;
  int wid = (blockIdx.x * blockDim.x + threadIdx.x) >> 6;
  int nw = (gridDim.x * blockDim.x) >> 6;
  for (int d = wid; d < N; d += nw) {
    int start = offs[d], end = offs[d + 1];
    float ax = 0.f, ay = 0.f;
    int e = start;
    for (; e + 8 <= end; e += 8) {
      int s0 = srcS[e],     s1 = srcS[e + 1], s2 = srcS[e + 2], s3 = srcS[e + 3];
      int s4 = srcS[e + 4], s5 = srcS[e + 5], s6 = srcS[e + 6], s7 = srcS[e + 7];
      float2 v0 = *(const float2*)(H + (size_t)s0 * 128 + lane * 2);
      float2 v1 = *(const float2*)(H + (size_t)s1 * 128 + lane * 2);
      float2 v2 = *(const float2*)(H + (size_t)s2 * 128 + lane * 2);
      float2 v3 = *(const float2*)(H + (size_t)s3 * 128 + lane * 2);
      float2 v4 = *(const float2*)(H + (size_t)s4 * 128 + lane * 2);
      float2 v5 = *(const float2*)(H + (size_t)s5 * 128 + lane * 2);
      float2 v6 = *(const float2*)(H + (size_t)s6 * 128 + lane * 2);
      float2 v7 = *(const float2*)(H + (size_t)s7 * 128 + lane * 2);
      ax += ((v0.x + v1.x) + (v2.x + v3.x)) + ((v4.x + v5.x) + (v6.x + v7.x));
      ay += ((v0.y + v1.y) + (v2.y + v3.y)) + ((v4.y + v5.y) + (v6.y + v7.y));
    }
    for (; e < end; ++e) {
      int s = srcS[e];
      float2 v = *(const float2*)(H + (size_t)s * 128 + lane * 2);
      ax += v.x; ay += v.y;
    }
    float w = poolw[d];
    int g = gid[d];
    float* ap = acc + g * DD + lane * 2;
    atomicAdd(ap, w * ax);       // ds_add_f32
    atomicAdd(ap + 1, w * ay);
  }
  __syncthreads();
  for (int i = threadIdx.x; i < GD; i += blockDim.x) {
    float v = acc[i];
    if (v != 0.f) gAtomAdd(&pooled[i], v);
  }
}

// ---- out = pooled @ W2 + b2  (tiny 64x128x128 GEMM) ----
__global__ __launch_bounds__(128) void k_out(const float* __restrict__ pooled, const float* __restrict__ W2,
                                             const float* __restrict__ b2, float* __restrict__ out) {
  __shared__ float p[DD];
  int g = blockIdx.x, d = threadIdx.x;
  p[d] = pooled[g * DD + d];
  __syncthreads();
  float a = b2[d];
#pragma unroll 4
  for (int k = 0; k < DD; ++k) a = fmaf(p[k], W2[k * DD + d], a);
  out[g * DD + d] = a;
}

extern "C" void kernel_launch(void* const* d_in, const int* in_sizes, int n_in,
                              void* d_out, int out_size, void* d_ws, size_t ws_size,
                              hipStream_t stream) {
  const float* X  = (const float*)d_in[0];
  const float* W1 = (const float*)d_in[1];
  const float* b1 = (const float*)d_in[2];
  const float* W2 = (const float*)d_in[3];
  const float* b2 = (const float*)d_in[4];
  const int* src  = (const int*)d_in[5];
  const int* dst  = (const int*)d_in[6];
  const int* gid  = (const int*)d_in[7];
  int E = in_sizes[5];
  int N = in_sizes[7];
  int G = out_size / DD;   // 64

  char* w = (char*)d_ws;
  size_t o = 0;
  auto carve = [&](size_t bytes) { char* p = w + o; o += (bytes + 255) & ~(size_t)255; return p; };
  // zero-init region (contiguous at start)
  int*   degO   = (int*)  carve((size_t)N * 4);
  int*   degI   = (int*)  carve((size_t)N * 4);
  int*   gcnt   = (int*)  carve((size_t)G * 4);
  float* pooled = (float*)carve((size_t)G * DD * 4);
  size_t zeroBytes = o;
  // rest
  float* nsrc   = (float*)carve((size_t)N * 4);
  float* ndst   = (float*)carve((size_t)N * 4);
  float* poolw  = (float*)carve((size_t)N * 4);
  int*   offs   = (int*)  carve((size_t)(N + 1) * 4);
  int*   cursor = (int*)  carve((size_t)N * 4);
  int*   bsum   = (int*)  carve(1024 * 4);
  int*   srcS   = (int*)  carve((size_t)E * 4);
  float* Z      = (float*)carve((size_t)N * DD * 4);
  float* H      = (float*)carve((size_t)N * DD * 4);

  hipMemsetAsync(d_ws, 0, zeroBytes, stream);

  k_deg<<<1024, 256, 0, stream>>>(src, dst, gid, degO, degI, gcnt, E, N, G);
  k_norm<<<(N + 255) / 256, 256, 0, stream>>>(degO, degI, gcnt, gid, nsrc, ndst, poolw, N);
  int B = (N + 255) / 256;                  // scan blocks (must be <= 1024)
  k_scanA<<<B, 256, 0, stream>>>(degI, offs, bsum, N);
  k_scanB<<<1, 1024, 0, stream>>>(bsum, B);
  k_scanC<<<B, 256, 0, stream>>>(offs, bsum, cursor, N, E);
  k_place<<<1024, 256, 0, stream>>>(src, dst, cursor, srcS, E);
  int rb = (N + 63) / 64;
  k_gemm1<<<rb * 2, 256, 0, stream>>>(X, W1, nsrc, Z, N);
  k_layer1<<<(N + 3) / 4, 256, 0, stream>>>(Z, offs, srcS, b1, nsrc, ndst, H, N);
  k_layer2<<<512, 1024, 0, stream>>>(H, offs, srcS, gid, poolw, pooled, N, G);
  k_out<<<G, DD, 0, stream>>>(pooled, W2, b2, (float*)d_out);
}

// Round 4
// 595.166 us; speedup vs baseline: 4.5053x; 1.1627x over previous
//
#include <hip/hip_runtime.h>
#include <cstdint>

// GCN via CSR (edges counting-sorted by dst) — no per-edge global f32 atomics.
// Z (=nsrc*X@W1) and H (=layer1 out) stored bf16: gathered tables are 25.6 MB
// each -> L2/L3 resident, gather bytes halved.
// Pooling commutes with @W2 -> final GEMM is [G,128]x[128,128] only.

#define DD 128

__device__ __forceinline__ void gAtomAdd(float* p, float v) { unsafeAtomicAdd(p, v); }

__device__ __forceinline__ unsigned short f2bf(float f) {
  union { float f; unsigned u; } v; v.f = f;
  unsigned r = (v.u + 0x7fff + ((v.u >> 16) & 1)) >> 16;   // round-nearest-even
  return (unsigned short)r;
}
__device__ __forceinline__ float bfhi(unsigned u) {  // high 16 bits as bf16
  union { unsigned u; float f; } v; v.u = u & 0xffff0000u; return v.f;
}
__device__ __forceinline__ float bflo(unsigned u) {  // low 16 bits as bf16
  union { unsigned u; float f; } v; v.u = u << 16; return v.f;
}

// ---- histograms: deg_out, deg_in (int), per-graph node counts ----
__global__ __launch_bounds__(256) void k_deg(const int* __restrict__ src, const int* __restrict__ dst,
                                             const int* __restrict__ gid,
                                             int* __restrict__ degO, int* __restrict__ degI,
                                             int* __restrict__ gcnt, int E, int N, int G) {
  __shared__ int scnt[64];
  if (threadIdx.x < 64) scnt[threadIdx.x] = 0;
  __syncthreads();
  int stride = gridDim.x * blockDim.x;
  for (int i = blockIdx.x * blockDim.x + threadIdx.x; i < E; i += stride) {
    atomicAdd(&degO[src[i]], 1);
    atomicAdd(&degI[dst[i]], 1);
  }
  for (int i = blockIdx.x * blockDim.x + threadIdx.x; i < N; i += stride)
    atomicAdd(&scnt[gid[i]], 1);
  __syncthreads();
  if (threadIdx.x < (unsigned)G) {
    int v = scnt[threadIdx.x];
    if (v) atomicAdd(&gcnt[threadIdx.x], v);
  }
}

// ---- norms + pooling weights ----
__global__ __launch_bounds__(256) void k_norm(const int* __restrict__ degO, const int* __restrict__ degI,
                                              const int* __restrict__ gcnt, const int* __restrict__ gid,
                                              float* __restrict__ nsrc, float* __restrict__ ndst,
                                              float* __restrict__ poolw, int N) {
  int i = blockIdx.x * blockDim.x + threadIdx.x;
  if (i >= N) return;
  float go = (float)degO[i]; go = go > 0.f ? go : 1.f;
  float gi = (float)degI[i]; gi = gi > 0.f ? gi : 1.f;
  float ns = rsqrtf(go), nd = rsqrtf(gi);
  nsrc[i] = ns; ndst[i] = nd;
  float c = (float)gcnt[gid[i]]; c = c > 1.f ? c : 1.f;
  poolw[i] = nd / c;
}

// ---- scan phase A ----
__global__ __launch_bounds__(256) void k_scanA(const int* __restrict__ degI, int* __restrict__ offs,
                                               int* __restrict__ bsum, int N) {
  __shared__ int s[256];
  int i = blockIdx.x * 256 + threadIdx.x;
  int v = (i < N) ? degI[i] : 0;
  s[threadIdx.x] = v;
  __syncthreads();
  for (int off = 1; off < 256; off <<= 1) {
    int x = (threadIdx.x >= off) ? s[threadIdx.x - off] : 0;
    __syncthreads();
    s[threadIdx.x] += x;
    __syncthreads();
  }
  if (i < N) offs[i] = s[threadIdx.x] - v;
  if (threadIdx.x == 255) bsum[blockIdx.x] = s[255];
}

// ---- scan phase B (single block, B <= 1024) ----
__global__ __launch_bounds__(1024) void k_scanB(int* __restrict__ bsum, int B) {
  __shared__ int s[1024];
  int v = (threadIdx.x < (unsigned)B) ? bsum[threadIdx.x] : 0;
  s[threadIdx.x] = v;
  __syncthreads();
  for (int off = 1; off < 1024; off <<= 1) {
    int x = (threadIdx.x >= off) ? s[threadIdx.x - off] : 0;
    __syncthreads();
    s[threadIdx.x] += x;
    __syncthreads();
  }
  if (threadIdx.x < (unsigned)B) bsum[threadIdx.x] = s[threadIdx.x] - v;
}

// ---- scan phase C ----
__global__ __launch_bounds__(256) void k_scanC(int* __restrict__ offs, const int* __restrict__ bsum,
                                               int* __restrict__ cursor, int N, int E) {
  int i = blockIdx.x * 256 + threadIdx.x;
  if (i < N) {
    int o = offs[i] + bsum[blockIdx.x];
    offs[i] = o;
    cursor[i] = o;
  }
  if (i == 0) offs[N] = E;
}

// ---- placement: bucket src indices by dst ----
__global__ __launch_bounds__(256) void k_place(const int* __restrict__ src, const int* __restrict__ dst,
                                               int* __restrict__ cursor, int* __restrict__ srcS, int E) {
  int stride = gridDim.x * blockDim.x;
  for (int e = blockIdx.x * blockDim.x + threadIdx.x; e < E; e += stride) {
    int d = dst[e];
    int p = atomicAdd(&cursor[d], 1);
    srcS[p] = src[e];
  }
}

// ---- GEMM1: Zb = bf16( (X @ W1) * nsrc[row] ) ----
__global__ __launch_bounds__(256) void k_gemm1(const float* __restrict__ X, const float* __restrict__ W,
                                               const float* __restrict__ nsrc,
                                               unsigned short* __restrict__ Zb, int N) {
  __shared__ float Wl[128 * 64];
  __shared__ float Xl[64 * 128];
  int bid = blockIdx.x;
  int rb = bid >> 1, ch = bid & 1;
  int row0 = rb * 64;
  int t = threadIdx.x;
  for (int i = t; i < 128 * 16; i += 256) {
    int r = i >> 4, c4 = i & 15;
    float4 v = *(const float4*)(W + r * 128 + ch * 64 + c4 * 4);
    *(float4*)(Wl + r * 64 + c4 * 4) = v;
  }
  for (int i = t; i < 64 * 32; i += 256) {
    int r = i >> 5, c4 = i & 31;
    int row = row0 + r; if (row >= N) row = N - 1;
    float4 v = *(const float4*)(X + (size_t)row * 128 + c4 * 4);
    *(float4*)(Xl + r * 128 + c4 * 4) = v;
  }
  __syncthreads();
  int tx = t & 31, ty = t >> 5;
  float acc[8][2] = {};
  for (int k = 0; k < 128; k += 4) {
    float4 xv[8];
#pragma unroll
    for (int rr = 0; rr < 8; ++rr) xv[rr] = *(const float4*)(Xl + (ty * 8 + rr) * 128 + k);
#pragma unroll
    for (int kk = 0; kk < 4; ++kk) {
      float w0 = Wl[(k + kk) * 64 + tx];
      float w1 = Wl[(k + kk) * 64 + tx + 32];
#pragma unroll
      for (int rr = 0; rr < 8; ++rr) {
        float x = ((const float*)&xv[rr])[kk];
        acc[rr][0] = fmaf(x, w0, acc[rr][0]);
        acc[rr][1] = fmaf(x, w1, acc[rr][1]);
      }
    }
  }
#pragma unroll
  for (int rr = 0; rr < 8; ++rr) {
    int row = row0 + ty * 8 + rr;
    if (row < N) {
      float s = nsrc[row];
      Zb[(size_t)row * 128 + ch * 64 + tx]      = f2bf(acc[rr][0] * s);
      Zb[(size_t)row * 128 + ch * 64 + tx + 32] = f2bf(acc[rr][1] * s);
    }
  }
}

// ---- layer1: per-dst gather-reduce (bf16 rows, half-wave pairs) + fused post-op ----
// lane half (0/1) handles edge e+half; lanes l32 cover 4 features each via uint2 (8B).
__global__ __launch_bounds__(256) void k_layer1(const unsigned short* __restrict__ Zb,
                                                const int* __restrict__ offs, const int* __restrict__ srcS,
                                                const float* __restrict__ b1,
                                                const float* __restrict__ nsrc, const float* __restrict__ ndst,
                                                unsigned short* __restrict__ Hb, int N) {
  int lane = threadIdx.x & 63;
  int half = lane >> 5, l32 = lane & 31;
  int d = blockIdx.x * 4 + (threadIdx.x >> 6);
  if (d >= N) return;
  int start = offs[d], end = offs[d + 1];
  float a0 = 0.f, a1 = 0.f, a2 = 0.f, a3 = 0.f;
  int e = start;
  for (; e + 8 <= end; e += 8) {             // 4 pairs in flight
    int s0 = srcS[e + half], s1 = srcS[e + 2 + half];
    int s2 = srcS[e + 4 + half], s3 = srcS[e + 6 + half];
    uint2 u0 = *(const uint2*)(Zb + (size_t)s0 * 128 + l32 * 4);
    uint2 u1 = *(const uint2*)(Zb + (size_t)s1 * 128 + l32 * 4);
    uint2 u2 = *(const uint2*)(Zb + (size_t)s2 * 128 + l32 * 4);
    uint2 u3 = *(const uint2*)(Zb + (size_t)s3 * 128 + l32 * 4);
    a0 += (bflo(u0.x) + bflo(u1.x)) + (bflo(u2.x) + bflo(u3.x));
    a1 += (bfhi(u0.x) + bfhi(u1.x)) + (bfhi(u2.x) + bfhi(u3.x));
    a2 += (bflo(u0.y) + bflo(u1.y)) + (bflo(u2.y) + bflo(u3.y));
    a3 += (bfhi(u0.y) + bfhi(u1.y)) + (bfhi(u2.y) + bfhi(u3.y));
  }
  for (; e + 2 <= end; e += 2) {
    int s = srcS[e + half];
    uint2 u = *(const uint2*)(Zb + (size_t)s * 128 + l32 * 4);
    a0 += bflo(u.x); a1 += bfhi(u.x); a2 += bflo(u.y); a3 += bfhi(u.y);
  }
  if (e < end && half == 0) {
    int s = srcS[e];
    uint2 u = *(const uint2*)(Zb + (size_t)s * 128 + l32 * 4);
    a0 += bflo(u.x); a1 += bfhi(u.x); a2 += bflo(u.y); a3 += bfhi(u.y);
  }
  a0 += __shfl_xor(a0, 32, 64);
  a1 += __shfl_xor(a1, 32, 64);
  a2 += __shfl_xor(a2, 32, 64);
  a3 += __shfl_xor(a3, 32, 64);
  if (half == 0) {
    float nd = ndst[d], ns = nsrc[d];
    int f = l32 * 4;
    float h0 = fmaxf(fmaf(nd, a0, b1[f + 0]), 0.f) * ns;
    float h1 = fmaxf(fmaf(nd, a1, b1[f + 1]), 0.f) * ns;
    float h2 = fmaxf(fmaf(nd, a2, b1[f + 2]), 0.f) * ns;
    float h3 = fmaxf(fmaf(nd, a3, b1[f + 3]), 0.f) * ns;
    ushort4 o; o.x = f2bf(h0); o.y = f2bf(h1); o.z = f2bf(h2); o.w = f2bf(h3);
    *(ushort4*)(Hb + (size_t)d * 128 + f) = o;
  }
}

// ---- layer2: per-dst gather-reduce (bf16), weighted LDS pool accumulate ----
__global__ __launch_bounds__(1024, 8) void k_layer2(const unsigned short* __restrict__ Hb,
                                                    const int* __restrict__ offs, const int* __restrict__ srcS,
                                                    const int* __restrict__ gid,
                                                    const float* __restrict__ poolw, float* __restrict__ pooled,
                                                    int N, int G) {
  __shared__ float acc[64 * DD];  // 32 KB
  int GD = G * DD;
  for (int i = threadIdx.x; i < GD; i += blockDim.x) acc[i] = 0.f;
  __syncthreads();
  int lane = threadIdx.x & 63;
  int half = lane >> 5, l32 = lane & 31;
  int wid = (blockIdx.x * blockDim.x + threadIdx.x) >> 6;
  int nw = (gridDim.x * blockDim.x) >> 6;
  for (int d = wid; d < N; d += nw) {
    int start = offs[d], end = offs[d + 1];
    float a0 = 0.f, a1 = 0.f, a2 = 0.f, a3 = 0.f;
    int e = start;
    for (; e + 8 <= end; e += 8) {
      int s0 = srcS[e + half], s1 = srcS[e + 2 + half];
      int s2 = srcS[e + 4 + half], s3 = srcS[e + 6 + half];
      uint2 u0 = *(const uint2*)(Hb + (size_t)s0 * 128 + l32 * 4);
      uint2 u1 = *(const uint2*)(Hb + (size_t)s1 * 128 + l32 * 4);
      uint2 u2 = *(const uint2*)(Hb + (size_t)s2 * 128 + l32 * 4);
      uint2 u3 = *(const uint2*)(Hb + (size_t)s3 * 128 + l32 * 4);
      a0 += (bflo(u0.x) + bflo(u1.x)) + (bflo(u2.x) + bflo(u3.x));
      a1 += (bfhi(u0.x) + bfhi(u1.x)) + (bfhi(u2.x) + bfhi(u3.x));
      a2 += (bflo(u0.y) + bflo(u1.y)) + (bflo(u2.y) + bflo(u3.y));
      a3 += (bfhi(u0.y) + bfhi(u1.y)) + (bfhi(u2.y) + bfhi(u3.y));
    }
    for (; e + 2 <= end; e += 2) {
      int s = srcS[e + half];
      uint2 u = *(const uint2*)(Hb + (size_t)s * 128 + l32 * 4);
      a0 += bflo(u.x); a1 += bfhi(u.x); a2 += bflo(u.y); a3 += bfhi(u.y);
    }
    if (e < end && half == 0) {
      int s = srcS[e];
      uint2 u = *(const uint2*)(Hb + (size_t)s * 128 + l32 * 4);
      a0 += bflo(u.x); a1 += bfhi(u.x); a2 += bflo(u.y); a3 += bfhi(u.y);
    }
    a0 += __shfl_xor(a0, 32, 64);
    a1 += __shfl_xor(a1, 32, 64);
    a2 += __shfl_xor(a2, 32, 64);
    a3 += __shfl_xor(a3, 32, 64);
    float w = poolw[d];
    int g = gid[d];
    float* ap = acc + g * DD + l32 * 4;
    if (half == 0) { atomicAdd(ap + 0, w * a0); atomicAdd(ap + 1, w * a1); }
    else           { atomicAdd(ap + 2, w * a2); atomicAdd(ap + 3, w * a3); }
  }
  __syncthreads();
  for (int i = threadIdx.x; i < GD; i += blockDim.x) {
    float v = acc[i];
    if (v != 0.f) gAtomAdd(&pooled[i], v);
  }
}

// ---- out = pooled @ W2 + b2 ----
__global__ __launch_bounds__(128) void k_out(const float* __restrict__ pooled, const float* __restrict__ W2,
                                             const float* __restrict__ b2, float* __restrict__ out) {
  __shared__ float p[DD];
  int g = blockIdx.x, d = threadIdx.x;
  p[d] = pooled[g * DD + d];
  __syncthreads();
  float a = b2[d];
#pragma unroll 4
  for (int k = 0; k < DD; ++k) a = fmaf(p[k], W2[k * DD + d], a);
  out[g * DD + d] = a;
}

extern "C" void kernel_launch(void* const* d_in, const int* in_sizes, int n_in,
                              void* d_out, int out_size, void* d_ws, size_t ws_size,
                              hipStream_t stream) {
  const float* X  = (const float*)d_in[0];
  const float* W1 = (const float*)d_in[1];
  const float* b1 = (const float*)d_in[2];
  const float* W2 = (const float*)d_in[3];
  const float* b2 = (const float*)d_in[4];
  const int* src  = (const int*)d_in[5];
  const int* dst  = (const int*)d_in[6];
  const int* gid  = (const int*)d_in[7];
  int E = in_sizes[5];
  int N = in_sizes[7];
  int G = out_size / DD;   // 64

  char* w = (char*)d_ws;
  size_t o = 0;
  auto carve = [&](size_t bytes) { char* p = w + o; o += (bytes + 255) & ~(size_t)255; return p; };
  // zero-init region (contiguous at start)
  int*   degO   = (int*)  carve((size_t)N * 4);
  int*   degI   = (int*)  carve((size_t)N * 4);
  int*   gcnt   = (int*)  carve((size_t)G * 4);
  float* pooled = (float*)carve((size_t)G * DD * 4);
  size_t zeroBytes = o;
  // rest
  float* nsrc   = (float*)carve((size_t)N * 4);
  float* ndst   = (float*)carve((size_t)N * 4);
  float* poolw  = (float*)carve((size_t)N * 4);
  int*   offs   = (int*)  carve((size_t)(N + 1) * 4);
  int*   cursor = (int*)  carve((size_t)N * 4);
  int*   bsum   = (int*)  carve(1024 * 4);
  int*   srcS   = (int*)  carve((size_t)E * 4);
  unsigned short* Zb = (unsigned short*)carve((size_t)N * DD * 2);
  unsigned short* Hb = (unsigned short*)carve((size_t)N * DD * 2);

  hipMemsetAsync(d_ws, 0, zeroBytes, stream);

  k_deg<<<2048, 256, 0, stream>>>(src, dst, gid, degO, degI, gcnt, E, N, G);
  k_norm<<<(N + 255) / 256, 256, 0, stream>>>(degO, degI, gcnt, gid, nsrc, ndst, poolw, N);
  int B = (N + 255) / 256;                  // scan blocks (must be <= 1024)
  k_scanA<<<B, 256, 0, stream>>>(degI, offs, bsum, N);
  k_scanB<<<1, 1024, 0, stream>>>(bsum, B);
  k_scanC<<<B, 256, 0, stream>>>(offs, bsum, cursor, N, E);
  k_place<<<2048, 256, 0, stream>>>(src, dst, cursor, srcS, E);
  int rb = (N + 63) / 64;
  k_gemm1<<<rb * 2, 256, 0, stream>>>(X, W1, nsrc, Zb, N);
  k_layer1<<<(N + 3) / 4, 256, 0, stream>>>(Zb, offs, srcS, b1, nsrc, ndst, Hb, N);
  k_layer2<<<512, 1024, 0, stream>>>(Hb, offs, srcS, gid, poolw, pooled, N, G);
  k_out<<<G, DD, 0, stream>>>(pooled, W2, b2, (float*)d_out);
}